// Round 2
// baseline (22476.736 us; speedup 1.0000x reference)
//
#include <hip/hip_runtime.h>
#include <hip/hip_bf16.h>

// RNN scan: T=1024, B=64, D_IN=1024, H=1024, fp32.
// out = [carry (64*1024)] ++ [outs (1024*64*1024)]
//
// Phase 1: xproj = xs @ Wih + bih  -> written into outs region of d_out.
// Phase 2: 1024 per-step dispatches (graph nodes). h_t lives in outs[t]
//          (in-place over xproj), so no workspace and no grid barrier:
//          inter-dispatch ordering gives the scan dependency.

#define T_STEPS 1024
#define BATCH   64
#define HDIM    1024

// ---------- small float4 helpers ----------
__device__ __forceinline__ float4 f4fma(float s, float4 v, float4 a) {
    a.x = fmaf(s, v.x, a.x);
    a.y = fmaf(s, v.y, a.y);
    a.z = fmaf(s, v.z, a.z);
    a.w = fmaf(s, v.w, a.w);
    return a;
}
__device__ __forceinline__ float4 f4add(float4 a, float4 b) {
    return make_float4(a.x + b.x, a.y + b.y, a.z + b.z, a.w + b.w);
}
__device__ __forceinline__ float fast_tanh(float x) {
    float ax = fabsf(x);
    float e  = __expf(2.0f * ax);          // v_exp_f32-based
    float r  = 1.0f - __fdividef(2.0f, e + 1.0f);
    return copysignf(r, x);
}
__device__ __forceinline__ float4 tanh4(float4 u) {
    return make_float4(fast_tanh(u.x), fast_tanh(u.y), fast_tanh(u.z), fast_tanh(u.w));
}

// ---------- Phase 1: xproj GEMM (fp32, 128x128 tile, 8x8 micro) ----------
// C[r, n] = sum_k A[r,k] * W[k,n] + bias[n];  M=65536, N=K=1024
__global__ __launch_bounds__(256) void xproj_gemm(
    const float* __restrict__ A,     // xs   [65536,1024]
    const float* __restrict__ W,     // Wih  [1024,1024]
    const float* __restrict__ bias,  // bih  [1024]
    float* __restrict__ C)           // outs [65536,1024]
{
    constexpr int K = 1024, N = 1024;
    __shared__ __align__(16) float As[8][132];
    __shared__ __align__(16) float Ws[8][132];

    const int tid = threadIdx.x;
    const int m0 = blockIdx.y * 128;
    const int n0 = blockIdx.x * 128;
    const int tx = tid & 15;          // 0..15 -> col groups
    const int ty = tid >> 4;          // 0..15 -> row groups

    // staging assignments
    const int arow = tid >> 1;            // 0..127
    const int kq   = (tid & 1) * 4;       // 0 or 4
    const int wrow = tid >> 5;            // 0..7
    const int wcol = (tid & 31) * 4;      // 0..124

    float4 c[2][4][2];
#pragma unroll
    for (int rb = 0; rb < 2; ++rb)
#pragma unroll
        for (int i = 0; i < 4; ++i)
#pragma unroll
            for (int cb = 0; cb < 2; ++cb)
                c[rb][i][cb] = make_float4(0.f, 0.f, 0.f, 0.f);

    for (int k0 = 0; k0 < K; k0 += 8) {
        float4 av = *(const float4*)(A + (size_t)(m0 + arow) * K + k0 + kq);
        float4 wv = *(const float4*)(W + (size_t)(k0 + wrow) * N + n0 + wcol);
        __syncthreads();
        As[kq + 0][arow] = av.x;
        As[kq + 1][arow] = av.y;
        As[kq + 2][arow] = av.z;
        As[kq + 3][arow] = av.w;
        *(float4*)&Ws[wrow][wcol] = wv;
        __syncthreads();
#pragma unroll
        for (int kk = 0; kk < 8; ++kk) {
            float4 a0 = *(const float4*)&As[kk][ty * 4];
            float4 a1 = *(const float4*)&As[kk][64 + ty * 4];
            float4 b0 = *(const float4*)&Ws[kk][tx * 4];
            float4 b1 = *(const float4*)&Ws[kk][64 + tx * 4];
            float a0a[4] = {a0.x, a0.y, a0.z, a0.w};
            float a1a[4] = {a1.x, a1.y, a1.z, a1.w};
#pragma unroll
            for (int i = 0; i < 4; ++i) {
                c[0][i][0] = f4fma(a0a[i], b0, c[0][i][0]);
                c[0][i][1] = f4fma(a0a[i], b1, c[0][i][1]);
                c[1][i][0] = f4fma(a1a[i], b0, c[1][i][0]);
                c[1][i][1] = f4fma(a1a[i], b1, c[1][i][1]);
            }
        }
    }

    float4 bv0 = *(const float4*)(bias + n0 + tx * 4);
    float4 bv1 = *(const float4*)(bias + n0 + 64 + tx * 4);
#pragma unroll
    for (int rb = 0; rb < 2; ++rb)
#pragma unroll
        for (int i = 0; i < 4; ++i) {
            int row = m0 + rb * 64 + ty * 4 + i;
            float* cp = C + (size_t)row * N + n0;
            *(float4*)(cp + tx * 4)      = f4add(c[rb][i][0], bv0);
            *(float4*)(cp + 64 + tx * 4) = f4add(c[rb][i][1], bv1);
        }
}

// ---------- Phase 2: one dispatch per step ----------
// grid 256 WGs x 512 threads. WG owns 4 output columns (jbase..jbase+3),
// 8 waves split K (128 each), lane b = batch row. W-row pointers are
// wave-uniform (readfirstlane) -> scalar loads; h rows stream as float4.
// out_t holds xproj on entry, h_t on exit (same thread reads & writes).
__global__ __launch_bounds__(512) void step_kernel(
    const float* __restrict__ Whh,    // [1024,1024]
    const float* __restrict__ bhh,    // [1024]
    const float* __restrict__ h_prev, // [64,1024]  (init or outs[t-1])
    float* __restrict__ out_t,        // [64,1024]  xp in, h out (in place)
    float* __restrict__ carry)        // d_out base on last step, else null
{
    const int tid = threadIdx.x;
    const int wg  = blockIdx.x;                                // 0..255
    const int b   = tid & 63;                                  // batch row
    const int ks  = __builtin_amdgcn_readfirstlane(tid >> 6);  // wave 0..7
    const int jbase = wg * 4;

    __shared__ __align__(16) float part[7][64][4];

    const float* hrow = h_prev + b * HDIM + ks * 128;          // per-lane stream
    const float* wp   = Whh + (size_t)(ks * 128) * HDIM + jbase; // wave-uniform

    float4 acc = make_float4(0.f, 0.f, 0.f, 0.f);
#pragma unroll 4
    for (int k = 0; k < 128; k += 4) {
        float4 hv = *(const float4*)(hrow + k);
        float4 w0 = *(const float4*)(wp + (size_t)(k + 0) * HDIM);
        float4 w1 = *(const float4*)(wp + (size_t)(k + 1) * HDIM);
        float4 w2 = *(const float4*)(wp + (size_t)(k + 2) * HDIM);
        float4 w3 = *(const float4*)(wp + (size_t)(k + 3) * HDIM);
        acc = f4fma(hv.x, w0, acc);
        acc = f4fma(hv.y, w1, acc);
        acc = f4fma(hv.z, w2, acc);
        acc = f4fma(hv.w, w3, acc);
    }

    if (ks > 0) {
        *(float4*)&part[ks - 1][b][0] = acc;
    }
    __syncthreads();
    if (ks == 0) {
#pragma unroll
        for (int i = 0; i < 7; ++i)
            acc = f4add(acc, *(const float4*)&part[i][b][0]);

        float4 bb = *(const float4*)(bhh + jbase);
        float* orow = out_t + b * HDIM + jbase;
        float4 xp = *(const float4*)orow;
        float4 u  = f4add(f4add(xp, acc), bb);
        float4 hv4 = tanh4(u);
        *(float4*)orow = hv4;                       // h_t lives in outs[t]
        if (carry != nullptr)
            *(float4*)(carry + b * HDIM + jbase) = hv4;
    }
}

extern "C" void kernel_launch(void* const* d_in, const int* in_sizes, int n_in,
                              void* d_out, int out_size, void* d_ws, size_t ws_size,
                              hipStream_t stream) {
    const float* init = (const float*)d_in[0];
    const float* xs   = (const float*)d_in[1];
    const float* Wih  = (const float*)d_in[2];
    const float* bih  = (const float*)d_in[3];
    const float* Whh  = (const float*)d_in[4];
    const float* bhh  = (const float*)d_in[5];
    float* out  = (float*)d_out;
    float* outs = out + BATCH * HDIM;   // [T][B][H]
    (void)d_ws; (void)ws_size;

    // Phase 1: xproj -> outs region of d_out (in-place workspace)
    xproj_gemm<<<dim3(8, 512), 256, 0, stream>>>(xs, Wih, bih, outs);

    // Phase 2: sequential per-step dispatches; h_t stored in outs[t]
    for (int t = 0; t < T_STEPS; ++t) {
        const float* hp = (t == 0) ? init : outs + (size_t)(t - 1) * BATCH * HDIM;
        float* ot = outs + (size_t)t * BATCH * HDIM;
        float* cr = (t == T_STEPS - 1) ? out : nullptr;
        step_kernel<<<dim3(256), 512, 0, stream>>>(Whh, bhh, hp, ot, cr);
    }
}